// Round 1
// baseline (829.467 us; speedup 1.0000x reference)
//
#include <hip/hip_runtime.h>
#include <hip/hip_bf16.h>

// Problem constants (match reference setup_inputs)
constexpr int Bc  = 32;
constexpr int Nc  = 2048;
constexpr int Hc  = 128;
constexpr int H4c = 512;
constexpr int BNc = Bc * Nc;   // 65536 rows

__device__ __forceinline__ float sigf(float x) {
    x = fminf(15.f, fmaxf(-15.f, x));
    return 1.f / (1.f + __expf(-x));
}
__device__ __forceinline__ float tanh_(float x) {
    x = fminf(15.f, fmaxf(-15.f, x));
    float e = __expf(2.f * x);
    return (e - 1.f) / (e + 1.f);
}

// ---------------------------------------------------------------------------
// Fused 2-layer LSTM over all B*N rows.
// Block: 256 threads, 32 rows. Thread t: j = t&127 (hidden dim), half = t>>7
// owns rows [half*16, half*16+16). Each thread computes gate cols
// {j, j+128, j+256, j+384} so the LSTM activation is fully in-register.
// W matrices (1 MB total) stream from L2; x/h rows staged in LDS.
// ---------------------------------------------------------------------------
__global__ __launch_bounds__(256) void lstm_kernel(
    const float* __restrict__ x_in,  const float* __restrict__ c0_in,
    const float* __restrict__ h0_in, const float* __restrict__ c1_in,
    const float* __restrict__ h1_in,
    const float* __restrict__ Wx0, const float* __restrict__ Wh0, const float* __restrict__ b0,
    const float* __restrict__ Wx1, const float* __restrict__ Wh1, const float* __restrict__ b1,
    const int* __restrict__ exit_i, const int* __restrict__ raise_i,
    float* __restrict__ contrib)
{
    __shared__ __align__(16) float xs[32][128];
    __shared__ __align__(16) float hs[32][128];

    const int t     = threadIdx.x;
    const int j     = t & 127;
    const int half  = t >> 7;
    const int rbase = half * 16;
    const int row0  = blockIdx.x * 32;
    const int bidx  = row0 >> 11;          // batch (Nc = 2048 rows per batch)
    const int eb    = exit_i[bidx];
    const int rbn   = raise_i[bidx];

    // stage x (node_embeddings) and h0
    {
        float4* xs4 = (float4*)xs;
        float4* hs4 = (float4*)hs;
        const float4* xg = (const float4*)(x_in  + (size_t)row0 * Hc);
        const float4* hg = (const float4*)(h0_in + (size_t)row0 * Hc);
        #pragma unroll
        for (int i = 0; i < 4; ++i) {
            xs4[t + i * 256] = xg[t + i * 256];
            hs4[t + i * 256] = hg[t + i * 256];
        }
    }
    __syncthreads();

    float acc[16][4];
    float hstash[16];

    // ---------------- layer 0 ----------------
    {
        float bias[4];
        #pragma unroll
        for (int c = 0; c < 4; ++c) bias[c] = b0[c * 128 + j];
        #pragma unroll
        for (int r = 0; r < 16; ++r)
            #pragma unroll
            for (int c = 0; c < 4; ++c) acc[r][c] = bias[c];

        for (int k = 0; k < 128; k += 4) {
            float wx[4][4], wh[4][4];   // [gate][kk]
            #pragma unroll
            for (int kk = 0; kk < 4; ++kk)
                #pragma unroll
                for (int c = 0; c < 4; ++c) {
                    wx[c][kk] = Wx0[(k + kk) * H4c + c * 128 + j];
                    wh[c][kk] = Wh0[(k + kk) * H4c + c * 128 + j];
                }
            #pragma unroll
            for (int r = 0; r < 16; ++r) {
                float4 xv = *(const float4*)&xs[rbase + r][k];
                float4 hv = *(const float4*)&hs[rbase + r][k];
                #pragma unroll
                for (int c = 0; c < 4; ++c) {
                    acc[r][c] += xv.x * wx[c][0] + xv.y * wx[c][1]
                               + xv.z * wx[c][2] + xv.w * wx[c][3]
                               + hv.x * wh[c][0] + hv.y * wh[c][1]
                               + hv.z * wh[c][2] + hv.w * wh[c][3];
                }
            }
        }
        // activations + masked contrib write (components 0:c0n, 1:h0n)
        #pragma unroll
        for (int r = 0; r < 16; ++r) {
            const int rr   = rbase + r;
            const int grow = row0 + rr;
            const int n    = grow & (Nc - 1);
            const bool keep = (n == eb) || (n == rbn);
            float c0v = c0_in[(size_t)grow * Hc + j];
            float ig = sigf(acc[r][0]);
            float fg = sigf(acc[r][1]);
            float gg = tanh_(acc[r][2]);
            float og = sigf(acc[r][3]);
            float cn = fg * c0v + ig * gg;
            float hn = og * tanh_(cn);
            float h0v = hs[rr][j];
            contrib[(size_t)grow * H4c + j]       = keep ? c0v : cn;
            contrib[(size_t)grow * H4c + 128 + j] = keep ? h0v : hn;
            hstash[r] = hn;   // layer-1 input uses UNMASKED h0n (matches ref)
        }
    }
    __syncthreads();
    #pragma unroll
    for (int r = 0; r < 16; ++r) {
        const int rr   = rbase + r;
        const int grow = row0 + rr;
        xs[rr][j] = hstash[r];
        hs[rr][j] = h1_in[(size_t)grow * Hc + j];
    }
    __syncthreads();

    // ---------------- layer 1 ----------------
    {
        float bias[4];
        #pragma unroll
        for (int c = 0; c < 4; ++c) bias[c] = b1[c * 128 + j];
        #pragma unroll
        for (int r = 0; r < 16; ++r)
            #pragma unroll
            for (int c = 0; c < 4; ++c) acc[r][c] = bias[c];

        for (int k = 0; k < 128; k += 4) {
            float wx[4][4], wh[4][4];
            #pragma unroll
            for (int kk = 0; kk < 4; ++kk)
                #pragma unroll
                for (int c = 0; c < 4; ++c) {
                    wx[c][kk] = Wx1[(k + kk) * H4c + c * 128 + j];
                    wh[c][kk] = Wh1[(k + kk) * H4c + c * 128 + j];
                }
            #pragma unroll
            for (int r = 0; r < 16; ++r) {
                float4 xv = *(const float4*)&xs[rbase + r][k];
                float4 hv = *(const float4*)&hs[rbase + r][k];
                #pragma unroll
                for (int c = 0; c < 4; ++c) {
                    acc[r][c] += xv.x * wx[c][0] + xv.y * wx[c][1]
                               + xv.z * wx[c][2] + xv.w * wx[c][3]
                               + hv.x * wh[c][0] + hv.y * wh[c][1]
                               + hv.z * wh[c][2] + hv.w * wh[c][3];
                }
            }
        }
        #pragma unroll
        for (int r = 0; r < 16; ++r) {
            const int rr   = rbase + r;
            const int grow = row0 + rr;
            const int n    = grow & (Nc - 1);
            const bool keep = (n == eb) || (n == rbn);
            float c1v = c1_in[(size_t)grow * Hc + j];
            float ig = sigf(acc[r][0]);
            float fg = sigf(acc[r][1]);
            float gg = tanh_(acc[r][2]);
            float og = sigf(acc[r][3]);
            float cn = fg * c1v + ig * gg;
            float hn = og * tanh_(cn);
            float h1v = hs[rr][j];
            contrib[(size_t)grow * H4c + 256 + j] = keep ? c1v : cn;
            contrib[(size_t)grow * H4c + 384 + j] = keep ? h1v : hn;
        }
    }
}

// ---------------------------------------------------------------------------
// Decision kernel: one wave per (b,n) row. emb[512] . {raise_W, branch_W},
// 2-way softmax, exit override, multiply by instruction pointer.
// w_all layout: [0]=p_raise*ip (raise edges), [1]=p_true*ip, [2]=p_false*ip.
// ---------------------------------------------------------------------------
__global__ __launch_bounds__(256) void dec_kernel(
    const float* __restrict__ contrib,
    const float* __restrict__ rW, const float* __restrict__ rbv,
    const float* __restrict__ bW, const float* __restrict__ bbv,
    const float* __restrict__ ip_in, const int* __restrict__ exit_i,
    float* __restrict__ w_all)
{
    const int gtid = blockIdx.x * 256 + threadIdx.x;
    const int wid  = gtid >> 6;
    const int l    = gtid & 63;

    const float* e = contrib + (size_t)wid * 512 + l * 8;
    float4 e0 = *(const float4*)e;
    float4 e1 = *(const float4*)(e + 4);
    const float4* r4 = (const float4*)(rW + l * 16);   // rows l*8..l*8+7, 2 cols
    const float4* b4 = (const float4*)(bW + l * 16);
    float4 ra = r4[0], rb_ = r4[1], rc = r4[2], rd = r4[3];
    float4 ba = b4[0], bb_ = b4[1], bc = b4[2], bd = b4[3];

    float pr0 = e0.x*ra.x + e0.y*ra.z + e0.z*rb_.x + e0.w*rb_.z
              + e1.x*rc.x + e1.y*rc.z + e1.z*rd.x  + e1.w*rd.z;
    float pr1 = e0.x*ra.y + e0.y*ra.w + e0.z*rb_.y + e0.w*rb_.w
              + e1.x*rc.y + e1.y*rc.w + e1.z*rd.y  + e1.w*rd.w;
    float pb0 = e0.x*ba.x + e0.y*ba.z + e0.z*bb_.x + e0.w*bb_.z
              + e1.x*bc.x + e1.y*bc.z + e1.z*bd.x  + e1.w*bd.z;
    float pb1 = e0.x*ba.y + e0.y*ba.w + e0.z*bb_.y + e0.w*bb_.w
              + e1.x*bc.y + e1.y*bc.w + e1.z*bd.y  + e1.w*bd.w;

    #pragma unroll
    for (int s = 1; s < 64; s <<= 1) {
        pr0 += __shfl_xor(pr0, s);
        pr1 += __shfl_xor(pr1, s);
        pb0 += __shfl_xor(pb0, s);
        pb1 += __shfl_xor(pb1, s);
    }

    if (l == 0) {
        const int bidx = wid >> 11;
        const int n    = wid & (Nc - 1);
        float r0v = pr0 + rbv[0], r1v = pr1 + rbv[1];
        float m  = fmaxf(r0v, r1v);
        float z0 = __expf(r0v - m), z1 = __expf(r1v - m);
        float inv = 1.f / (z0 + z1);
        float praise = z0 * inv, pno = z1 * inv;
        if (n == exit_i[bidx]) { praise = 0.f; pno = 1.f; }
        float q0 = pb0 + bbv[0], q1 = pb1 + bbv[1];
        float mm = fmaxf(q0, q1);
        float y0 = __expf(q0 - mm), y1 = __expf(q1 - mm);
        float binv = 1.f / (y0 + y1);
        float ipv = ip_in[wid];
        w_all[wid]            = praise * ipv;
        w_all[BNc + wid]      = pno * y0 * binv * ipv;
        w_all[2 * BNc + wid]  = pno * y1 * binv * ipv;
    }
}

// ---------------------------------------------------------------------------
// Invert the scatter into per-target linked lists.
// Edge id e = row*4 + type, type: 0=raise, 1=true, 2=false.
// ---------------------------------------------------------------------------
__global__ __launch_bounds__(256) void build_kernel(
    const int* __restrict__ t_idx, const int* __restrict__ f_idx,
    const int* __restrict__ r_idx, int* __restrict__ head, int* __restrict__ nxt)
{
    const int row  = blockIdx.x * 256 + threadIdx.x;
    const int base = (row >> 11) << 11;   // b * Nc
    const int e0 = row * 4;
    int o;
    o = atomicExch(&head[base + r_idx[row]], e0);     nxt[e0]     = o;
    o = atomicExch(&head[base + t_idx[row]], e0 + 1); nxt[e0 + 1] = o;
    o = atomicExch(&head[base + f_idx[row]], e0 + 2); nxt[e0 + 2] = o;
}

// ---------------------------------------------------------------------------
// Gather: one wave per target (b,m). Walk incoming edge list, accumulate
// weighted contrib rows + ip mass; divide, apply live gate, pack output row.
// ---------------------------------------------------------------------------
__global__ __launch_bounds__(256) void gather_kernel(
    const float* __restrict__ contrib, const float* __restrict__ w_all,
    const int* __restrict__ head, const int* __restrict__ nxt,
    const float* __restrict__ c0_in, const float* __restrict__ h0_in,
    const float* __restrict__ c1_in, const float* __restrict__ h1_in,
    const float* __restrict__ ip_in,
    const int* __restrict__ cstep, const int* __restrict__ slim,
    float* __restrict__ out)
{
    const int gtid = blockIdx.x * 256 + threadIdx.x;
    const int wid  = gtid >> 6;
    const int l    = gtid & 63;
    const int bidx = wid >> 11;

    float acc[8] = {0.f, 0.f, 0.f, 0.f, 0.f, 0.f, 0.f, 0.f};
    float ipsum = 0.f;

    int e = head[wid];
    while (e >= 0) {
        const int src = e >> 2;
        const float w = w_all[(e & 3) * BNc + src];
        const float* crow = contrib + (size_t)src * 512;
        #pragma unroll
        for (int q = 0; q < 8; ++q) acc[q] += w * crow[q * 64 + l];
        ipsum += w;
        e = nxt[e];
    }

    const bool live = cstep[bidx] < slim[bidx];
    float* orow = out + (size_t)wid * 513;
    if (live) {
        const float inv = 1.f / (ipsum + 1e-7f);
        #pragma unroll
        for (int q = 0; q < 8; ++q) orow[q * 64 + l] = acc[q] * inv;
        if (l == 0) orow[512] = ipsum;
    } else {
        const float* oldp0 = c0_in; const float* oldp1 = h0_in;
        const float* oldp2 = c1_in; const float* oldp3 = h1_in;
        #pragma unroll
        for (int q = 0; q < 8; ++q) {
            const int off = (q & 1) * 64 + l;
            const float* p = (q >> 1) == 0 ? oldp0 : (q >> 1) == 1 ? oldp1
                           : (q >> 1) == 2 ? oldp2 : oldp3;
            orow[q * 64 + l] = p[(size_t)wid * Hc + off];
        }
        if (l == 0) orow[512] = ip_in[wid];
    }
}

extern "C" void kernel_launch(void* const* d_in, const int* in_sizes, int n_in,
                              void* d_out, int out_size, void* d_ws, size_t ws_size,
                              hipStream_t stream) {
    const float* x     = (const float*)d_in[0];
    const float* c0    = (const float*)d_in[1];
    const float* h0    = (const float*)d_in[2];
    const float* c1    = (const float*)d_in[3];
    const float* h1    = (const float*)d_in[4];
    const float* ip    = (const float*)d_in[5];
    const float* Wx0   = (const float*)d_in[6];
    const float* Wh0   = (const float*)d_in[7];
    const float* b0    = (const float*)d_in[8];
    const float* Wx1   = (const float*)d_in[9];
    const float* Wh1   = (const float*)d_in[10];
    const float* b1    = (const float*)d_in[11];
    const float* rW    = (const float*)d_in[12];
    const float* rb    = (const float*)d_in[13];
    const float* bW    = (const float*)d_in[14];
    const float* bb    = (const float*)d_in[15];
    const int* t_idx   = (const int*)d_in[16];
    const int* f_idx   = (const int*)d_in[17];
    const int* r_idx   = (const int*)d_in[18];
    const int* exit_i  = (const int*)d_in[19];
    const int* raise_i = (const int*)d_in[20];
    const int* cstep   = (const int*)d_in[21];
    const int* slim    = (const int*)d_in[22];
    float* out = (float*)d_out;

    // workspace layout
    float* contrib = (float*)d_ws;                       // BN*512 f32 (128 MiB)
    float* w_all   = contrib + (size_t)BNc * 512;        // 3*BN f32
    int*   head    = (int*)(w_all + 3 * (size_t)BNc);    // BN int
    int*   nxt     = head + BNc;                         // 4*BN int

    hipMemsetAsync(head, 0xFF, BNc * sizeof(int), stream);   // head = -1

    lstm_kernel<<<BNc / 32, 256, 0, stream>>>(x, c0, h0, c1, h1,
                                              Wx0, Wh0, b0, Wx1, Wh1, b1,
                                              exit_i, raise_i, contrib);
    dec_kernel<<<BNc / 4, 256, 0, stream>>>(contrib, rW, rb, bW, bb, ip, exit_i, w_all);
    build_kernel<<<BNc / 256, 256, 0, stream>>>(t_idx, f_idx, r_idx, head, nxt);
    gather_kernel<<<BNc / 4, 256, 0, stream>>>(contrib, w_all, head, nxt,
                                               c0, h0, c1, h1, ip, cstep, slim, out);
}

// Round 2
// 345.010 us; speedup vs baseline: 2.4042x; 2.4042x over previous
//
#include <hip/hip_runtime.h>
#include <hip/hip_bf16.h>

// Problem constants (match reference setup_inputs)
constexpr int Bc  = 32;
constexpr int Nc  = 2048;
constexpr int Hc  = 128;
constexpr int H4c = 512;
constexpr int BNc = Bc * Nc;   // 65536 rows

typedef __attribute__((ext_vector_type(8))) short short8;
typedef __attribute__((ext_vector_type(4))) float f32x4;

__device__ __forceinline__ float sigf(float x) {
    x = fminf(15.f, fmaxf(-15.f, x));
    return 1.f / (1.f + __expf(-x));
}
__device__ __forceinline__ float tanh_(float x) {
    x = fminf(15.f, fmaxf(-15.f, x));
    float e = __expf(2.f * x);
    return (e - 1.f) / (e + 1.f);
}
// f32 -> bf16 bits (RNE, matches HW)
__device__ __forceinline__ unsigned short bfu(float f) {
    union { float f; unsigned u; } a; a.f = f;
    unsigned u = a.u;
    return (unsigned short)((u + 0x7FFFu + ((u >> 16) & 1u)) >> 16);
}
__device__ __forceinline__ float bf2f(unsigned short u) {
    union { unsigned u; float f; } a; a.u = ((unsigned)u) << 16;
    return a.f;
}

// ---------------------------------------------------------------------------
// Weight prep: W0T/W1T [col=512][k=256] bf16, k<128 from Wx, k>=128 from Wh.
// ---------------------------------------------------------------------------
__global__ __launch_bounds__(256) void prep_kernel(
    const float* __restrict__ Wx0, const float* __restrict__ Wh0,
    const float* __restrict__ Wx1, const float* __restrict__ Wh1,
    unsigned short* __restrict__ W0T, unsigned short* __restrict__ W1T)
{
    int e = blockIdx.x * 256 + threadIdx.x;   // 0..131071 = 512*256
    int col = e & 511;
    int k   = e >> 9;
    float v0 = (k < 128) ? Wx0[k * 512 + col] : Wh0[(k - 128) * 512 + col];
    float v1 = (k < 128) ? Wx1[k * 512 + col] : Wh1[(k - 128) * 512 + col];
    W0T[(size_t)col * 256 + k] = bfu(v0);
    W1T[(size_t)col * 256 + k] = bfu(v1);
}

// ---------------------------------------------------------------------------
// MFMA GEMM for one layer: A = As (LDS, [32 rows][264 bf16], k=0..255),
// B = WT [512 cols][256 k] bf16. Wave w owns cols {g*128 + jg*64 + w*16 + lr}
// so all 4 gates of hidden dim j = w*16+jg*64+lr live in this wave.
// acc[mt][jg][g]: rows mt*16 + (lg*4+reg), cols as above (16x16x32 tiles).
// ---------------------------------------------------------------------------
__device__ __forceinline__ void gemm16(
    const unsigned short* As, const unsigned short* __restrict__ WT,
    const float* __restrict__ bias, int wave, int lr, int lg,
    f32x4 (&acc)[2][2][4])
{
    #pragma unroll
    for (int jg = 0; jg < 2; ++jg)
        #pragma unroll
        for (int g = 0; g < 4; ++g) {
            float bv = bias[g * 128 + jg * 64 + wave * 16 + lr];
            f32x4 v = {bv, bv, bv, bv};
            acc[0][jg][g] = v;
            acc[1][jg][g] = v;
        }
    for (int ks = 0; ks < 8; ++ks) {
        const int kofs = (ks * 32 + lg * 8) * 2;   // bytes
        short8 a0 = *(const short8*)((const char*)As + lr * 528 + kofs);
        short8 a1 = *(const short8*)((const char*)As + (16 + lr) * 528 + kofs);
        #pragma unroll
        for (int jg = 0; jg < 2; ++jg)
            #pragma unroll
            for (int g = 0; g < 4; ++g) {
                const int col = g * 128 + jg * 64 + wave * 16 + lr;
                short8 b = *(const short8*)(WT + (size_t)col * 256 + ks * 32 + lg * 8);
                acc[0][jg][g] = __builtin_amdgcn_mfma_f32_16x16x32_bf16(a0, b, acc[0][jg][g], 0, 0, 0);
                acc[1][jg][g] = __builtin_amdgcn_mfma_f32_16x16x32_bf16(a1, b, acc[1][jg][g], 0, 0, 0);
            }
    }
}

// ---------------------------------------------------------------------------
// Fused 2-layer LSTM, MFMA version. Block: 256 threads / 4 waves / 32 rows.
// ---------------------------------------------------------------------------
__global__ __launch_bounds__(256) void lstm_mfma_kernel(
    const float* __restrict__ x_in,  const float* __restrict__ c0_in,
    const float* __restrict__ h0_in, const float* __restrict__ c1_in,
    const float* __restrict__ h1_in,
    const unsigned short* __restrict__ W0T, const unsigned short* __restrict__ W1T,
    const float* __restrict__ b0, const float* __restrict__ b1,
    const int* __restrict__ exit_i, const int* __restrict__ raise_i,
    unsigned short* __restrict__ contrib)
{
    __shared__ __align__(16) unsigned short As[32 * 264];   // row stride 528 B

    const int t    = threadIdx.x;
    const int wave = t >> 6, l = t & 63, lr = l & 15, lg = l >> 4;
    const int row0 = blockIdx.x * 32;
    const int bidx = row0 >> 11;
    const int eb   = exit_i[bidx];
    const int rbn  = raise_i[bidx];

    // stage x (k 0..127) and h0 (k 128..255) as bf16
    #pragma unroll
    for (int i = 0; i < 4; ++i) {
        int idx = t + i * 256;              // 0..1023
        int row = idx >> 5, c4 = idx & 31;  // 32 float4 per row
        float4 xv = ((const float4*)(x_in  + (size_t)(row0 + row) * Hc))[c4];
        float4 hv = ((const float4*)(h0_in + (size_t)(row0 + row) * Hc))[c4];
        ushort4 xb = { bfu(xv.x), bfu(xv.y), bfu(xv.z), bfu(xv.w) };
        ushort4 hb = { bfu(hv.x), bfu(hv.y), bfu(hv.z), bfu(hv.w) };
        *(ushort4*)((char*)As + row * 528 + c4 * 8)       = xb;
        *(ushort4*)((char*)As + row * 528 + 256 + c4 * 8) = hb;
    }
    __syncthreads();

    f32x4 acc[2][2][4];
    gemm16(As, W0T, b0, wave, lr, lg, acc);
    __syncthreads();   // all waves done reading As before overwrite

    // layer-0 activations; write masked contrib; rebuild As = [h0n_raw | h1]
    #pragma unroll
    for (int mt = 0; mt < 2; ++mt)
        #pragma unroll
        for (int jg = 0; jg < 2; ++jg) {
            const int j = wave * 16 + jg * 64 + lr;
            #pragma unroll
            for (int r = 0; r < 4; ++r) {
                const int rib  = mt * 16 + lg * 4 + r;
                const int grow = row0 + rib;
                const int n    = grow & (Nc - 1);
                float ig = sigf(acc[mt][jg][0][r]);
                float fg = sigf(acc[mt][jg][1][r]);
                float gv = tanh_(acc[mt][jg][2][r]);
                float og = sigf(acc[mt][jg][3][r]);
                float cold = c0_in[(size_t)grow * Hc + j];
                float cn = fg * cold + ig * gv;
                float hn = og * tanh_(cn);
                // layer-1 inputs (UNMASKED h0n, old h1)
                *(unsigned short*)((char*)As + rib * 528 + j * 2) = bfu(hn);
                float h1v = h1_in[(size_t)grow * Hc + j];
                *(unsigned short*)((char*)As + rib * 528 + (128 + j) * 2) = bfu(h1v);
                bool keep = (n == eb) || (n == rbn);
                float cw = cn, hw = hn;
                if (keep) { cw = cold; hw = h0_in[(size_t)grow * Hc + j]; }
                contrib[(size_t)grow * H4c + j]       = bfu(cw);
                contrib[(size_t)grow * H4c + 128 + j] = bfu(hw);
            }
        }
    __syncthreads();

    gemm16(As, W1T, b1, wave, lr, lg, acc);

    // layer-1 activations (registers only; no As access)
    #pragma unroll
    for (int mt = 0; mt < 2; ++mt)
        #pragma unroll
        for (int jg = 0; jg < 2; ++jg) {
            const int j = wave * 16 + jg * 64 + lr;
            #pragma unroll
            for (int r = 0; r < 4; ++r) {
                const int rib  = mt * 16 + lg * 4 + r;
                const int grow = row0 + rib;
                const int n    = grow & (Nc - 1);
                float ig = sigf(acc[mt][jg][0][r]);
                float fg = sigf(acc[mt][jg][1][r]);
                float gv = tanh_(acc[mt][jg][2][r]);
                float og = sigf(acc[mt][jg][3][r]);
                float cold = c1_in[(size_t)grow * Hc + j];
                float cn = fg * cold + ig * gv;
                float hn = og * tanh_(cn);
                bool keep = (n == eb) || (n == rbn);
                float cw = cn, hw = hn;
                if (keep) { cw = cold; hw = h1_in[(size_t)grow * Hc + j]; }
                contrib[(size_t)grow * H4c + 256 + j] = bfu(cw);
                contrib[(size_t)grow * H4c + 384 + j] = bfu(hw);
            }
        }
}

// ---------------------------------------------------------------------------
// Decision kernel: one wave per (b,n) row (contrib now bf16).
// w_all: [0]=p_raise*ip, [1]=p_true*ip, [2]=p_false*ip.
// ---------------------------------------------------------------------------
__global__ __launch_bounds__(256) void dec_kernel(
    const unsigned short* __restrict__ contrib,
    const float* __restrict__ rW, const float* __restrict__ rbv,
    const float* __restrict__ bW, const float* __restrict__ bbv,
    const float* __restrict__ ip_in, const int* __restrict__ exit_i,
    float* __restrict__ w_all)
{
    const int gtid = blockIdx.x * 256 + threadIdx.x;
    const int wid  = gtid >> 6;
    const int l    = gtid & 63;

    short8 ev = *(const short8*)(contrib + (size_t)wid * 512 + l * 8);
    float ef[8];
    #pragma unroll
    for (int q = 0; q < 8; ++q) ef[q] = bf2f((unsigned short)ev[q]);

    const float4* r4 = (const float4*)(rW + l * 16);   // rows l*8..l*8+7, 2 cols
    const float4* b4 = (const float4*)(bW + l * 16);
    float4 ra = r4[0], rb_ = r4[1], rc = r4[2], rd = r4[3];
    float4 ba = b4[0], bb_ = b4[1], bc = b4[2], bd = b4[3];

    float pr0 = ef[0]*ra.x + ef[1]*ra.z + ef[2]*rb_.x + ef[3]*rb_.z
              + ef[4]*rc.x + ef[5]*rc.z + ef[6]*rd.x  + ef[7]*rd.z;
    float pr1 = ef[0]*ra.y + ef[1]*ra.w + ef[2]*rb_.y + ef[3]*rb_.w
              + ef[4]*rc.y + ef[5]*rc.w + ef[6]*rd.y  + ef[7]*rd.w;
    float pb0 = ef[0]*ba.x + ef[1]*ba.z + ef[2]*bb_.x + ef[3]*bb_.z
              + ef[4]*bc.x + ef[5]*bc.z + ef[6]*bd.x  + ef[7]*bd.z;
    float pb1 = ef[0]*ba.y + ef[1]*ba.w + ef[2]*bb_.y + ef[3]*bb_.w
              + ef[4]*bc.y + ef[5]*bc.w + ef[6]*bd.y  + ef[7]*bd.w;

    #pragma unroll
    for (int s = 1; s < 64; s <<= 1) {
        pr0 += __shfl_xor(pr0, s);
        pr1 += __shfl_xor(pr1, s);
        pb0 += __shfl_xor(pb0, s);
        pb1 += __shfl_xor(pb1, s);
    }

    if (l == 0) {
        const int bidx = wid >> 11;
        const int n    = wid & (Nc - 1);
        float r0v = pr0 + rbv[0], r1v = pr1 + rbv[1];
        float m  = fmaxf(r0v, r1v);
        float z0 = __expf(r0v - m), z1 = __expf(r1v - m);
        float inv = 1.f / (z0 + z1);
        float praise = z0 * inv, pno = z1 * inv;
        if (n == exit_i[bidx]) { praise = 0.f; pno = 1.f; }
        float q0 = pb0 + bbv[0], q1 = pb1 + bbv[1];
        float mm = fmaxf(q0, q1);
        float y0 = __expf(q0 - mm), y1 = __expf(q1 - mm);
        float binv = 1.f / (y0 + y1);
        float ipv = ip_in[wid];
        w_all[wid]            = praise * ipv;
        w_all[BNc + wid]      = pno * y0 * binv * ipv;
        w_all[2 * BNc + wid]  = pno * y1 * binv * ipv;
    }
}

// ---------------------------------------------------------------------------
// Invert the scatter into per-target linked lists. e = row*4 + type.
// ---------------------------------------------------------------------------
__global__ __launch_bounds__(256) void build_kernel(
    const int* __restrict__ t_idx, const int* __restrict__ f_idx,
    const int* __restrict__ r_idx, int* __restrict__ head, int* __restrict__ nxt)
{
    const int row  = blockIdx.x * 256 + threadIdx.x;
    const int base = (row >> 11) << 11;
    const int e0 = row * 4;
    int o;
    o = atomicExch(&head[base + r_idx[row]], e0);     nxt[e0]     = o;
    o = atomicExch(&head[base + t_idx[row]], e0 + 1); nxt[e0 + 1] = o;
    o = atomicExch(&head[base + f_idx[row]], e0 + 2); nxt[e0 + 2] = o;
}

// ---------------------------------------------------------------------------
// Gather: one wave per target (b,m). bf16 contrib rows, f32 accumulate.
// ---------------------------------------------------------------------------
__global__ __launch_bounds__(256) void gather_kernel(
    const unsigned short* __restrict__ contrib, const float* __restrict__ w_all,
    const int* __restrict__ head, const int* __restrict__ nxt,
    const float* __restrict__ c0_in, const float* __restrict__ h0_in,
    const float* __restrict__ c1_in, const float* __restrict__ h1_in,
    const float* __restrict__ ip_in,
    const int* __restrict__ cstep, const int* __restrict__ slim,
    float* __restrict__ out)
{
    const int gtid = blockIdx.x * 256 + threadIdx.x;
    const int wid  = gtid >> 6;
    const int l    = gtid & 63;
    const int bidx = wid >> 11;

    float acc[8] = {0.f, 0.f, 0.f, 0.f, 0.f, 0.f, 0.f, 0.f};
    float ipsum = 0.f;

    int e = head[wid];
    while (e >= 0) {
        const int src = e >> 2;
        const float w = w_all[(e & 3) * BNc + src];
        const unsigned short* crow = contrib + (size_t)src * 512;
        #pragma unroll
        for (int q = 0; q < 8; ++q) acc[q] += w * bf2f(crow[q * 64 + l]);
        ipsum += w;
        e = nxt[e];
    }

    const bool live = cstep[bidx] < slim[bidx];
    float* orow = out + (size_t)wid * 513;
    if (live) {
        const float inv = 1.f / (ipsum + 1e-7f);
        #pragma unroll
        for (int q = 0; q < 8; ++q) orow[q * 64 + l] = acc[q] * inv;
        if (l == 0) orow[512] = ipsum;
    } else {
        #pragma unroll
        for (int q = 0; q < 8; ++q) {
            const int off = (q & 1) * 64 + l;
            const float* p = (q >> 1) == 0 ? c0_in : (q >> 1) == 1 ? h0_in
                           : (q >> 1) == 2 ? c1_in : h1_in;
            orow[q * 64 + l] = p[(size_t)wid * Hc + off];
        }
        if (l == 0) orow[512] = ip_in[wid];
    }
}

extern "C" void kernel_launch(void* const* d_in, const int* in_sizes, int n_in,
                              void* d_out, int out_size, void* d_ws, size_t ws_size,
                              hipStream_t stream) {
    const float* x     = (const float*)d_in[0];
    const float* c0    = (const float*)d_in[1];
    const float* h0    = (const float*)d_in[2];
    const float* c1    = (const float*)d_in[3];
    const float* h1    = (const float*)d_in[4];
    const float* ip    = (const float*)d_in[5];
    const float* Wx0   = (const float*)d_in[6];
    const float* Wh0   = (const float*)d_in[7];
    const float* b0    = (const float*)d_in[8];
    const float* Wx1   = (const float*)d_in[9];
    const float* Wh1   = (const float*)d_in[10];
    const float* b1    = (const float*)d_in[11];
    const float* rW    = (const float*)d_in[12];
    const float* rb    = (const float*)d_in[13];
    const float* bW    = (const float*)d_in[14];
    const float* bb    = (const float*)d_in[15];
    const int* t_idx   = (const int*)d_in[16];
    const int* f_idx   = (const int*)d_in[17];
    const int* r_idx   = (const int*)d_in[18];
    const int* exit_i  = (const int*)d_in[19];
    const int* raise_i = (const int*)d_in[20];
    const int* cstep   = (const int*)d_in[21];
    const int* slim    = (const int*)d_in[22];
    float* out = (float*)d_out;

    // workspace layout
    unsigned short* contrib = (unsigned short*)d_ws;            // BN*512 bf16 (64 MiB)
    unsigned short* W0T = contrib + (size_t)BNc * 512;          // 512*256 bf16
    unsigned short* W1T = W0T + 512 * 256;
    float* w_all = (float*)(W1T + 512 * 256);                   // 3*BN f32
    int*   head  = (int*)(w_all + 3 * (size_t)BNc);             // BN int
    int*   nxt   = head + BNc;                                  // 4*BN int

    hipMemsetAsync(head, 0xFF, BNc * sizeof(int), stream);

    prep_kernel<<<512, 256, 0, stream>>>(Wx0, Wh0, Wx1, Wh1, W0T, W1T);
    lstm_mfma_kernel<<<BNc / 32, 256, 0, stream>>>(x, c0, h0, c1, h1,
                                                   W0T, W1T, b0, b1,
                                                   exit_i, raise_i, contrib);
    dec_kernel<<<BNc / 4, 256, 0, stream>>>(contrib, rW, rb, bW, bb, ip, exit_i, w_all);
    build_kernel<<<BNc / 256, 256, 0, stream>>>(t_idx, f_idx, r_idx, head, nxt);
    gather_kernel<<<BNc / 4, 256, 0, stream>>>(contrib, w_all, head, nxt,
                                               c0, h0, c1, h1, ip, cstep, slim, out);
}

// Round 3
// 317.814 us; speedup vs baseline: 2.6099x; 1.0856x over previous
//
#include <hip/hip_runtime.h>
#include <hip/hip_bf16.h>

// Problem constants (match reference setup_inputs)
constexpr int Bc  = 32;
constexpr int Nc  = 2048;
constexpr int Hc  = 128;
constexpr int H4c = 512;
constexpr int BNc = Bc * Nc;   // 65536 rows

typedef __attribute__((ext_vector_type(8))) short short8;
typedef __attribute__((ext_vector_type(4))) float f32x4;

__device__ __forceinline__ float sigf(float x) {
    x = fminf(15.f, fmaxf(-15.f, x));
    return 1.f / (1.f + __expf(-x));
}
__device__ __forceinline__ float tanh_(float x) {
    x = fminf(15.f, fmaxf(-15.f, x));
    float e = __expf(2.f * x);
    return (e - 1.f) / (e + 1.f);
}
// f32 -> bf16 bits (RNE, matches HW)
__device__ __forceinline__ unsigned short bfu(float f) {
    union { float f; unsigned u; } a; a.f = f;
    unsigned u = a.u;
    return (unsigned short)((u + 0x7FFFu + ((u >> 16) & 1u)) >> 16);
}
__device__ __forceinline__ float bf2f(unsigned short u) {
    union { unsigned u; float f; } a; a.u = ((unsigned)u) << 16;
    return a.f;
}
__device__ __forceinline__ short8 pack8(float4 a, float4 b) {
    short8 o;
    o[0] = (short)bfu(a.x); o[1] = (short)bfu(a.y);
    o[2] = (short)bfu(a.z); o[3] = (short)bfu(a.w);
    o[4] = (short)bfu(b.x); o[5] = (short)bfu(b.y);
    o[6] = (short)bfu(b.z); o[7] = (short)bfu(b.w);
    return o;
}

// LDS A-tile: 128 rows x 32 units of 16B (256 bf16 k-values per row).
// XOR swizzle on the 16B unit index kills the stride-512B bank conflict:
// lanes reading the same logical unit across rows spread over 8 bank-quads.
__device__ __forceinline__ int lds_off(int row, int unit) {   // byte offset
    return row * 512 + ((unit ^ (row & 7)) << 4);
}

// ---------------------------------------------------------------------------
// Weight prep: W0T/W1T [col=512][k=256] bf16, k<128 from Wx, k>=128 from Wh.
// ---------------------------------------------------------------------------
__global__ __launch_bounds__(256) void prep_kernel(
    const float* __restrict__ Wx0, const float* __restrict__ Wh0,
    const float* __restrict__ Wx1, const float* __restrict__ Wh1,
    unsigned short* __restrict__ W0T, unsigned short* __restrict__ W1T)
{
    int e = blockIdx.x * 256 + threadIdx.x;   // 0..131071 = 512*256
    int col = e & 511;
    int k   = e >> 9;
    float v0 = (k < 128) ? Wx0[k * 512 + col] : Wh0[(k - 128) * 512 + col];
    float v1 = (k < 128) ? Wx1[k * 512 + col] : Wh1[(k - 128) * 512 + col];
    W0T[(size_t)col * 256 + k] = bfu(v0);
    W1T[(size_t)col * 256 + k] = bfu(v1);
}

// ---------------------------------------------------------------------------
// One-layer GEMM: A = LDS tile (128 rows x 256 k bf16, swizzled),
// B = WT [512 cols][256 k]. Wave owns cols {g*128 + wave*16 + lr}, g=0..3,
// i.e. all 4 gates of hidden dims j = wave*16 + 0..15.
// acc[mt][g]: rows mt*16 + lg*4 + r. B prefetched one ks ahead (registers).
// ---------------------------------------------------------------------------
__device__ __forceinline__ void gemm_big(
    const char* As, const unsigned short* __restrict__ WT,
    int wave, int lr, int lg, f32x4 (&acc)[8][4])
{
    const unsigned short* wp = WT + (size_t)(wave * 16 + lr) * 256 + lg * 8;
    short8 b[4], bn[4];
    #pragma unroll
    for (int g = 0; g < 4; ++g) bn[g] = *(const short8*)(wp + g * 32768);

    #pragma unroll
    for (int ks = 0; ks < 8; ++ks) {
        #pragma unroll
        for (int g = 0; g < 4; ++g) b[g] = bn[g];
        if (ks < 7) {
            #pragma unroll
            for (int g = 0; g < 4; ++g)
                bn[g] = *(const short8*)(wp + g * 32768 + (ks + 1) * 32);
        }
        short8 a[8];
        #pragma unroll
        for (int mt = 0; mt < 8; ++mt)
            a[mt] = *(const short8*)(As + lds_off(mt * 16 + lr, ks * 4 + lg));
        #pragma unroll
        for (int mt = 0; mt < 8; ++mt)
            #pragma unroll
            for (int g = 0; g < 4; ++g)
                acc[mt][g] = __builtin_amdgcn_mfma_f32_16x16x32_bf16(
                    a[mt], b[g], acc[mt][g], 0, 0, 0);
    }
}

// ---------------------------------------------------------------------------
// Fused 2-layer LSTM, MFMA. Block: 512 threads / 8 waves / 128 rows.
// ---------------------------------------------------------------------------
__global__ __launch_bounds__(512, 2) void lstm_mfma_kernel(
    const float* __restrict__ x_in,  const float* __restrict__ c0_in,
    const float* __restrict__ h0_in, const float* __restrict__ c1_in,
    const float* __restrict__ h1_in,
    const unsigned short* __restrict__ W0T, const unsigned short* __restrict__ W1T,
    const float* __restrict__ b0, const float* __restrict__ b1,
    const int* __restrict__ exit_i, const int* __restrict__ raise_i,
    unsigned short* __restrict__ contrib)
{
    __shared__ __align__(16) char As[128 * 512];   // 64 KiB

    const int t    = threadIdx.x;
    const int wave = t >> 6, l = t & 63, lr = l & 15, lg = l >> 4;
    const int row0 = blockIdx.x * 128;
    const int bidx = row0 >> 11;
    const int eb   = exit_i[bidx];
    const int rbn  = raise_i[bidx];
    const int j    = wave * 16 + lr;

    float bv0[4], bv1[4];
    #pragma unroll
    for (int g = 0; g < 4; ++g) { bv0[g] = b0[g * 128 + j]; bv1[g] = b1[g * 128 + j]; }

    // ---- stage x (units 0..15) and h0 (units 16..31) as bf16 ----
    {
        const int r = t >> 2, q = t & 3;
        const float4* xr = (const float4*)(x_in  + (size_t)(row0 + r) * Hc + q * 32);
        const float4* hr = (const float4*)(h0_in + (size_t)(row0 + r) * Hc + q * 32);
        #pragma unroll
        for (int i = 0; i < 4; ++i) {
            *(short8*)(As + lds_off(r, q * 4 + i))      = pack8(xr[i * 2], xr[i * 2 + 1]);
            *(short8*)(As + lds_off(r, 16 + q * 4 + i)) = pack8(hr[i * 2], hr[i * 2 + 1]);
        }
    }
    __syncthreads();

    f32x4 acc[8][4];
    #pragma unroll
    for (int mt = 0; mt < 8; ++mt)
        #pragma unroll
        for (int g = 0; g < 4; ++g) {
            f32x4 v = {bv0[g], bv0[g], bv0[g], bv0[g]};
            acc[mt][g] = v;
        }
    gemm_big(As, W0T, wave, lr, lg, acc);
    __syncthreads();   // everyone done reading As before in-place rebuild

    // ---- layer-0 activations; write masked contrib; rebuild As = [h0n | h1] ----
    #pragma unroll
    for (int mt = 0; mt < 8; ++mt) {
        #pragma unroll
        for (int rr = 0; rr < 4; ++rr) {
            const int rib  = mt * 16 + lg * 4 + rr;
            const int grow = row0 + rib;
            const int n    = grow & (Nc - 1);
            float ig = sigf(acc[mt][0][rr]);
            float fg = sigf(acc[mt][1][rr]);
            float gv = tanh_(acc[mt][2][rr]);
            float og = sigf(acc[mt][3][rr]);
            float cold = c0_in[(size_t)grow * Hc + j];
            float cn = fg * cold + ig * gv;
            float hn = og * tanh_(cn);
            // old h0 (bf16) read BEFORE overwriting the same bytes with h1
            unsigned short h0b =
                *(const unsigned short*)(As + lds_off(rib, 16 + (j >> 3)) + (j & 7) * 2);
            // layer-1 inputs: UNMASKED h0n at k=j, old h1 at k=128+j
            *(unsigned short*)(As + lds_off(rib, j >> 3) + (j & 7) * 2) = bfu(hn);
            float h1v = h1_in[(size_t)grow * Hc + j];
            *(unsigned short*)(As + lds_off(rib, 16 + (j >> 3)) + (j & 7) * 2) = bfu(h1v);
            const bool keep = (n == eb) || (n == rbn);
            contrib[(size_t)grow * H4c + j]       = keep ? bfu(cold) : bfu(cn);
            contrib[(size_t)grow * H4c + 128 + j] = keep ? h0b : bfu(hn);
        }
    }
    __syncthreads();

    #pragma unroll
    for (int mt = 0; mt < 8; ++mt)
        #pragma unroll
        for (int g = 0; g < 4; ++g) {
            f32x4 v = {bv1[g], bv1[g], bv1[g], bv1[g]};
            acc[mt][g] = v;
        }
    gemm_big(As, W1T, wave, lr, lg, acc);

    // ---- layer-1 activations (keep-h1 comes back from LDS) ----
    #pragma unroll
    for (int mt = 0; mt < 8; ++mt) {
        #pragma unroll
        for (int rr = 0; rr < 4; ++rr) {
            const int rib  = mt * 16 + lg * 4 + rr;
            const int grow = row0 + rib;
            const int n    = grow & (Nc - 1);
            float ig = sigf(acc[mt][0][rr]);
            float fg = sigf(acc[mt][1][rr]);
            float gv = tanh_(acc[mt][2][rr]);
            float og = sigf(acc[mt][3][rr]);
            float cold = c1_in[(size_t)grow * Hc + j];
            float cn = fg * cold + ig * gv;
            float hn = og * tanh_(cn);
            unsigned short h1b =
                *(const unsigned short*)(As + lds_off(rib, 16 + (j >> 3)) + (j & 7) * 2);
            const bool keep = (n == eb) || (n == rbn);
            contrib[(size_t)grow * H4c + 256 + j] = keep ? bfu(cold) : bfu(cn);
            contrib[(size_t)grow * H4c + 384 + j] = keep ? h1b : bfu(hn);
        }
    }
}

// ---------------------------------------------------------------------------
// Decision kernel: one wave per (b,n) row (contrib bf16).
// w_all: [0]=p_raise*ip, [1]=p_true*ip, [2]=p_false*ip.
// ---------------------------------------------------------------------------
__global__ __launch_bounds__(256) void dec_kernel(
    const unsigned short* __restrict__ contrib,
    const float* __restrict__ rW, const float* __restrict__ rbv,
    const float* __restrict__ bW, const float* __restrict__ bbv,
    const float* __restrict__ ip_in, const int* __restrict__ exit_i,
    float* __restrict__ w_all)
{
    const int gtid = blockIdx.x * 256 + threadIdx.x;
    const int wid  = gtid >> 6;
    const int l    = gtid & 63;

    short8 ev = *(const short8*)(contrib + (size_t)wid * 512 + l * 8);
    float ef[8];
    #pragma unroll
    for (int q = 0; q < 8; ++q) ef[q] = bf2f((unsigned short)ev[q]);

    const float4* r4 = (const float4*)(rW + l * 16);
    const float4* b4 = (const float4*)(bW + l * 16);
    float4 ra = r4[0], rb_ = r4[1], rc = r4[2], rd = r4[3];
    float4 ba = b4[0], bb_ = b4[1], bc = b4[2], bd = b4[3];

    float pr0 = ef[0]*ra.x + ef[1]*ra.z + ef[2]*rb_.x + ef[3]*rb_.z
              + ef[4]*rc.x + ef[5]*rc.z + ef[6]*rd.x  + ef[7]*rd.z;
    float pr1 = ef[0]*ra.y + ef[1]*ra.w + ef[2]*rb_.y + ef[3]*rb_.w
              + ef[4]*rc.y + ef[5]*rc.w + ef[6]*rd.y  + ef[7]*rd.w;
    float pb0 = ef[0]*ba.x + ef[1]*ba.z + ef[2]*bb_.x + ef[3]*bb_.z
              + ef[4]*bc.x + ef[5]*bc.z + ef[6]*bd.x  + ef[7]*bd.z;
    float pb1 = ef[0]*ba.y + ef[1]*ba.w + ef[2]*bb_.y + ef[3]*bb_.w
              + ef[4]*bc.y + ef[5]*bc.w + ef[6]*bd.y  + ef[7]*bd.w;

    #pragma unroll
    for (int s = 1; s < 64; s <<= 1) {
        pr0 += __shfl_xor(pr0, s);
        pr1 += __shfl_xor(pr1, s);
        pb0 += __shfl_xor(pb0, s);
        pb1 += __shfl_xor(pb1, s);
    }

    if (l == 0) {
        const int bidx = wid >> 11;
        const int n    = wid & (Nc - 1);
        float r0v = pr0 + rbv[0], r1v = pr1 + rbv[1];
        float m  = fmaxf(r0v, r1v);
        float z0 = __expf(r0v - m), z1 = __expf(r1v - m);
        float inv = 1.f / (z0 + z1);
        float praise = z0 * inv, pno = z1 * inv;
        if (n == exit_i[bidx]) { praise = 0.f; pno = 1.f; }
        float q0 = pb0 + bbv[0], q1 = pb1 + bbv[1];
        float mm = fmaxf(q0, q1);
        float y0 = __expf(q0 - mm), y1 = __expf(q1 - mm);
        float binv = 1.f / (y0 + y1);
        float ipv = ip_in[wid];
        w_all[wid]            = praise * ipv;
        w_all[BNc + wid]      = pno * y0 * binv * ipv;
        w_all[2 * BNc + wid]  = pno * y1 * binv * ipv;
    }
}

// ---------------------------------------------------------------------------
// Invert the scatter into per-target linked lists. e = row*4 + type.
// ---------------------------------------------------------------------------
__global__ __launch_bounds__(256) void build_kernel(
    const int* __restrict__ t_idx, const int* __restrict__ f_idx,
    const int* __restrict__ r_idx, int* __restrict__ head, int* __restrict__ nxt)
{
    const int row  = blockIdx.x * 256 + threadIdx.x;
    const int base = (row >> 11) << 11;
    const int e0 = row * 4;
    int o;
    o = atomicExch(&head[base + r_idx[row]], e0);     nxt[e0]     = o;
    o = atomicExch(&head[base + t_idx[row]], e0 + 1); nxt[e0 + 1] = o;
    o = atomicExch(&head[base + f_idx[row]], e0 + 2); nxt[e0 + 2] = o;
}

// ---------------------------------------------------------------------------
// Gather: one wave per target (b,m). bf16 contrib rows, f32 accumulate.
// ---------------------------------------------------------------------------
__global__ __launch_bounds__(256) void gather_kernel(
    const unsigned short* __restrict__ contrib, const float* __restrict__ w_all,
    const int* __restrict__ head, const int* __restrict__ nxt,
    const float* __restrict__ c0_in, const float* __restrict__ h0_in,
    const float* __restrict__ c1_in, const float* __restrict__ h1_in,
    const float* __restrict__ ip_in,
    const int* __restrict__ cstep, const int* __restrict__ slim,
    float* __restrict__ out)
{
    const int gtid = blockIdx.x * 256 + threadIdx.x;
    const int wid  = gtid >> 6;
    const int l    = gtid & 63;
    const int bidx = wid >> 11;

    float acc[8] = {0.f, 0.f, 0.f, 0.f, 0.f, 0.f, 0.f, 0.f};
    float ipsum = 0.f;

    int e = head[wid];
    while (e >= 0) {
        const int src = e >> 2;
        const float w = w_all[(e & 3) * BNc + src];
        const unsigned short* crow = contrib + (size_t)src * 512;
        #pragma unroll
        for (int q = 0; q < 8; ++q) acc[q] += w * bf2f(crow[q * 64 + l]);
        ipsum += w;
        e = nxt[e];
    }

    const bool live = cstep[bidx] < slim[bidx];
    float* orow = out + (size_t)wid * 513;
    if (live) {
        const float inv = 1.f / (ipsum + 1e-7f);
        #pragma unroll
        for (int q = 0; q < 8; ++q) orow[q * 64 + l] = acc[q] * inv;
        if (l == 0) orow[512] = ipsum;
    } else {
        #pragma unroll
        for (int q = 0; q < 8; ++q) {
            const int off = (q & 1) * 64 + l;
            const float* p = (q >> 1) == 0 ? c0_in : (q >> 1) == 1 ? h0_in
                           : (q >> 1) == 2 ? c1_in : h1_in;
            orow[q * 64 + l] = p[(size_t)wid * Hc + off];
        }
        if (l == 0) orow[512] = ip_in[wid];
    }
}

extern "C" void kernel_launch(void* const* d_in, const int* in_sizes, int n_in,
                              void* d_out, int out_size, void* d_ws, size_t ws_size,
                              hipStream_t stream) {
    const float* x     = (const float*)d_in[0];
    const float* c0    = (const float*)d_in[1];
    const float* h0    = (const float*)d_in[2];
    const float* c1    = (const float*)d_in[3];
    const float* h1    = (const float*)d_in[4];
    const float* ip    = (const float*)d_in[5];
    const float* Wx0   = (const float*)d_in[6];
    const float* Wh0   = (const float*)d_in[7];
    const float* b0    = (const float*)d_in[8];
    const float* Wx1   = (const float*)d_in[9];
    const float* Wh1   = (const float*)d_in[10];
    const float* b1    = (const float*)d_in[11];
    const float* rW    = (const float*)d_in[12];
    const float* rb    = (const float*)d_in[13];
    const float* bW    = (const float*)d_in[14];
    const float* bb    = (const float*)d_in[15];
    const int* t_idx   = (const int*)d_in[16];
    const int* f_idx   = (const int*)d_in[17];
    const int* r_idx   = (const int*)d_in[18];
    const int* exit_i  = (const int*)d_in[19];
    const int* raise_i = (const int*)d_in[20];
    const int* cstep   = (const int*)d_in[21];
    const int* slim    = (const int*)d_in[22];
    float* out = (float*)d_out;

    // workspace layout
    unsigned short* contrib = (unsigned short*)d_ws;            // BN*512 bf16 (64 MiB)
    unsigned short* W0T = contrib + (size_t)BNc * 512;          // 512*256 bf16
    unsigned short* W1T = W0T + 512 * 256;
    float* w_all = (float*)(W1T + 512 * 256);                   // 3*BN f32
    int*   head  = (int*)(w_all + 3 * (size_t)BNc);             // BN int
    int*   nxt   = head + BNc;                                  // 4*BN int

    hipMemsetAsync(head, 0xFF, BNc * sizeof(int), stream);

    prep_kernel<<<512, 256, 0, stream>>>(Wx0, Wh0, Wx1, Wh1, W0T, W1T);
    lstm_mfma_kernel<<<BNc / 128, 512, 0, stream>>>(x, c0, h0, c1, h1,
                                                    W0T, W1T, b0, b1,
                                                    exit_i, raise_i, contrib);
    dec_kernel<<<BNc / 4, 256, 0, stream>>>(contrib, rW, rb, bW, bb, ip, exit_i, w_all);
    build_kernel<<<BNc / 256, 256, 0, stream>>>(t_idx, f_idx, r_idx, head, nxt);
    gather_kernel<<<BNc / 4, 256, 0, stream>>>(contrib, w_all, head, nxt,
                                               c0, h0, c1, h1, ip, cstep, slim, out);
}

// Round 5
// 280.293 us; speedup vs baseline: 2.9593x; 1.1339x over previous
//
#include <hip/hip_runtime.h>
#include <hip/hip_bf16.h>

// Problem constants (match reference setup_inputs)
constexpr int Bc  = 32;
constexpr int Nc  = 2048;
constexpr int Hc  = 128;
constexpr int H4c = 512;
constexpr int BNc = Bc * Nc;   // 65536 rows

typedef __attribute__((ext_vector_type(8))) short short8;
typedef __attribute__((ext_vector_type(4))) float f32x4;

__device__ __forceinline__ float sigf(float x) {
    x = fminf(15.f, fmaxf(-15.f, x));
    return 1.f / (1.f + __expf(-x));
}
__device__ __forceinline__ float tanh_(float x) {
    x = fminf(15.f, fmaxf(-15.f, x));
    float e = __expf(2.f * x);
    return (e - 1.f) / (e + 1.f);
}
// f32 -> bf16 bits (RNE, matches HW)
__device__ __forceinline__ unsigned short bfu(float f) {
    union { float f; unsigned u; } a; a.f = f;
    unsigned u = a.u;
    return (unsigned short)((u + 0x7FFFu + ((u >> 16) & 1u)) >> 16);
}
__device__ __forceinline__ float bf2f(unsigned short u) {
    union { unsigned u; float f; } a; a.u = ((unsigned)u) << 16;
    return a.f;
}
__device__ __forceinline__ short8 pack8(float4 a, float4 b) {
    short8 o;
    o[0] = (short)bfu(a.x); o[1] = (short)bfu(a.y);
    o[2] = (short)bfu(a.z); o[3] = (short)bfu(a.w);
    o[4] = (short)bfu(b.x); o[5] = (short)bfu(b.y);
    o[6] = (short)bfu(b.z); o[7] = (short)bfu(b.w);
    return o;
}

// As tile: 32 rows x 32 units of 16B (256 bf16 k per row). XOR swizzle on the
// 16B unit index spreads same-unit column reads across 8 bank-quads.
__device__ __forceinline__ int lds_off(int row, int unit) {   // byte offset
    return row * 512 + ((unit ^ (row & 7)) << 4);
}
// Cs tile: 32 rows x 64 units of 16B (512 bf16 per row), same swizzle idea.
__device__ __forceinline__ int cs_off(int row, int unit) {    // byte offset
    return row * 1024 + ((unit ^ (row & 7)) << 4);
}

// ---------------------------------------------------------------------------
// Weight prep: W0T/W1T [col=512][k=256] bf16, k<128 from Wx, k>=128 from Wh.
// ---------------------------------------------------------------------------
__global__ __launch_bounds__(256) void prep_kernel(
    const float* __restrict__ Wx0, const float* __restrict__ Wh0,
    const float* __restrict__ Wx1, const float* __restrict__ Wh1,
    unsigned short* __restrict__ W0T, unsigned short* __restrict__ W1T)
{
    int e = blockIdx.x * 256 + threadIdx.x;   // 0..131071 = 512*256
    int col = e & 511;
    int k   = e >> 9;
    float v0 = (k < 128) ? Wx0[k * 512 + col] : Wh0[(k - 128) * 512 + col];
    float v1 = (k < 128) ? Wx1[k * 512 + col] : Wh1[(k - 128) * 512 + col];
    W0T[(size_t)col * 256 + k] = bfu(v0);
    W1T[(size_t)col * 256 + k] = bfu(v1);
}

// ---------------------------------------------------------------------------
// One-layer GEMM. A = As (32 rows x 256 k, swizzled LDS). B = WT [512][256].
// Wave owns cols {g*128 + jg*64 + wave*16 + lr}, g=0..3, jg=0..1 -> all 4
// gates of hidden dims j = jg*64 + wave*16 + lr (FULL 0..127 coverage).
// acc[mt][jg][g]: rows mt*16 + lg*4 + r.
// ---------------------------------------------------------------------------
__device__ __forceinline__ void gemm_big(
    const char* As, const unsigned short* __restrict__ WT,
    int wave, int lr, int lg, f32x4 (&acc)[2][2][4])
{
    const unsigned short* wp = WT + (size_t)(wave * 16 + lr) * 256 + lg * 8;
    #pragma unroll
    for (int ks = 0; ks < 8; ++ks) {
        short8 a[2];
        #pragma unroll
        for (int mt = 0; mt < 2; ++mt)
            a[mt] = *(const short8*)(As + lds_off(mt * 16 + lr, ks * 4 + lg));
        #pragma unroll
        for (int jg = 0; jg < 2; ++jg)
            #pragma unroll
            for (int g = 0; g < 4; ++g) {
                short8 b = *(const short8*)(wp + (size_t)(g * 128 + jg * 64) * 256 + ks * 32);
                #pragma unroll
                for (int mt = 0; mt < 2; ++mt)
                    acc[mt][jg][g] = __builtin_amdgcn_mfma_f32_16x16x32_bf16(
                        a[mt], b, acc[mt][jg][g], 0, 0, 0);
            }
    }
}

// ---------------------------------------------------------------------------
// Fused 2-layer LSTM + decision head. Block: 256 threads / 4 waves / 32 rows.
// contrib written via LDS restage (coalesced 16B stores); dec head fused
// (reads the Cs tile, writes w_all) so dec_kernel's 64MB re-read disappears.
// ---------------------------------------------------------------------------
__global__ __launch_bounds__(256, 3) void lstm_mfma_kernel(
    const float* __restrict__ x_in,  const float* __restrict__ c0_in,
    const float* __restrict__ h0_in, const float* __restrict__ c1_in,
    const float* __restrict__ h1_in,
    const unsigned short* __restrict__ W0T, const unsigned short* __restrict__ W1T,
    const float* __restrict__ b0, const float* __restrict__ b1,
    const float* __restrict__ rW, const float* __restrict__ rbv,
    const float* __restrict__ bW, const float* __restrict__ bbv,
    const float* __restrict__ ip_in,
    const int* __restrict__ exit_i, const int* __restrict__ raise_i,
    unsigned short* __restrict__ contrib, float* __restrict__ w_all)
{
    __shared__ __align__(16) char As[32 * 512];    // 16 KiB (A tile, later decW)
    __shared__ __align__(16) char Cs[32 * 1024];   // 32 KiB (contrib tile)

    const int t    = threadIdx.x;
    const int wave = t >> 6, l = t & 63, lr = l & 15, lg = l >> 4;
    const int row0 = blockIdx.x * 32;
    const int bidx = row0 >> 11;
    const int eb   = exit_i[bidx];
    const int rbn  = raise_i[bidx];

    // ---- stage x (units 0..15) and h0 (units 16..31) as bf16 ----
    {
        const int r = t >> 3, q = t & 7;
        #pragma unroll
        for (int i = 0; i < 4; ++i) {
            const int u = q * 4 + i;
            const float4* src = (u < 16)
                ? (const float4*)(x_in  + (size_t)(row0 + r) * Hc + u * 8)
                : (const float4*)(h0_in + (size_t)(row0 + r) * Hc + (u - 16) * 8);
            *(short8*)(As + lds_off(r, u)) = pack8(src[0], src[1]);
        }
    }

    // ---- preload c0, h1 (act0 inputs); latency overlaps staging ----
    float c0v[2][2][4], h1v[2][2][4];
    #pragma unroll
    for (int mt = 0; mt < 2; ++mt)
        #pragma unroll
        for (int jg = 0; jg < 2; ++jg)
            #pragma unroll
            for (int rr = 0; rr < 4; ++rr) {
                const int grow = row0 + mt * 16 + lg * 4 + rr;
                const int j = jg * 64 + wave * 16 + lr;
                c0v[mt][jg][rr] = c0_in[(size_t)grow * Hc + j];
                h1v[mt][jg][rr] = h1_in[(size_t)grow * Hc + j];
            }
    float bv0[2][4];
    #pragma unroll
    for (int jg = 0; jg < 2; ++jg)
        #pragma unroll
        for (int g = 0; g < 4; ++g)
            bv0[jg][g] = b0[g * 128 + jg * 64 + wave * 16 + lr];

    __syncthreads();

    f32x4 acc[2][2][4];
    #pragma unroll
    for (int mt = 0; mt < 2; ++mt)
        #pragma unroll
        for (int jg = 0; jg < 2; ++jg)
            #pragma unroll
            for (int g = 0; g < 4; ++g) {
                f32x4 v = {bv0[jg][g], bv0[jg][g], bv0[jg][g], bv0[jg][g]};
                acc[mt][jg][g] = v;
            }
    gemm_big(As, W0T, wave, lr, lg, acc);
    __syncthreads();   // all A-reads done before in-place rebuild

    // ---- preload c1 (hides under act0 + gemm1) ----
    float c1v[2][2][4];
    #pragma unroll
    for (int mt = 0; mt < 2; ++mt)
        #pragma unroll
        for (int jg = 0; jg < 2; ++jg)
            #pragma unroll
            for (int rr = 0; rr < 4; ++rr) {
                const int grow = row0 + mt * 16 + lg * 4 + rr;
                c1v[mt][jg][rr] = c1_in[(size_t)grow * Hc + jg * 64 + wave * 16 + lr];
            }

    // ---- act0: LSTM cell 0; Cs comps 0,1; rebuild As = [h0n | h1] ----
    #pragma unroll
    for (int mt = 0; mt < 2; ++mt)
        #pragma unroll
        for (int jg = 0; jg < 2; ++jg) {
            const int j = jg * 64 + wave * 16 + lr;
            #pragma unroll
            for (int rr = 0; rr < 4; ++rr) {
                const int rib  = mt * 16 + lg * 4 + rr;
                const int grow = row0 + rib;
                const int n    = grow & (Nc - 1);
                float ig = sigf(acc[mt][jg][0][rr]);
                float fg = sigf(acc[mt][jg][1][rr]);
                float gv = tanh_(acc[mt][jg][2][rr]);
                float og = sigf(acc[mt][jg][3][rr]);
                float cold = c0v[mt][jg][rr];
                float cn = fg * cold + ig * gv;
                float hn = og * tanh_(cn);
                // old h0 (bf16) read BEFORE overwriting that cell with h1
                unsigned short h0b =
                    *(const unsigned short*)(As + lds_off(rib, 16 + (j >> 3)) + (j & 7) * 2);
                *(unsigned short*)(As + lds_off(rib, j >> 3) + (j & 7) * 2) = bfu(hn);
                *(unsigned short*)(As + lds_off(rib, 16 + (j >> 3)) + (j & 7) * 2) =
                    bfu(h1v[mt][jg][rr]);
                const bool keep = (n == eb) || (n == rbn);
                *(unsigned short*)(Cs + cs_off(rib, j >> 3) + (j & 7) * 2) =
                    keep ? bfu(cold) : bfu(cn);
                *(unsigned short*)(Cs + cs_off(rib, 16 + (j >> 3)) + (j & 7) * 2) =
                    keep ? h0b : bfu(hn);
            }
        }
    __syncthreads();   // As rebuilt for layer 1

    float bv1[2][4];
    #pragma unroll
    for (int jg = 0; jg < 2; ++jg)
        #pragma unroll
        for (int g = 0; g < 4; ++g)
            bv1[jg][g] = b1[g * 128 + jg * 64 + wave * 16 + lr];
    #pragma unroll
    for (int mt = 0; mt < 2; ++mt)
        #pragma unroll
        for (int jg = 0; jg < 2; ++jg)
            #pragma unroll
            for (int g = 0; g < 4; ++g) {
                f32x4 v = {bv1[jg][g], bv1[jg][g], bv1[jg][g], bv1[jg][g]};
                acc[mt][jg][g] = v;
            }
    gemm_big(As, W1T, wave, lr, lg, acc);

    // ---- act1: LSTM cell 1; Cs comps 2,3 (keep-h1 read back from As) ----
    #pragma unroll
    for (int mt = 0; mt < 2; ++mt)
        #pragma unroll
        for (int jg = 0; jg < 2; ++jg) {
            const int j = jg * 64 + wave * 16 + lr;
            #pragma unroll
            for (int rr = 0; rr < 4; ++rr) {
                const int rib  = mt * 16 + lg * 4 + rr;
                const int grow = row0 + rib;
                const int n    = grow & (Nc - 1);
                float ig = sigf(acc[mt][jg][0][rr]);
                float fg = sigf(acc[mt][jg][1][rr]);
                float gv = tanh_(acc[mt][jg][2][rr]);
                float og = sigf(acc[mt][jg][3][rr]);
                float cold = c1v[mt][jg][rr];
                float cn = fg * cold + ig * gv;
                float hn = og * tanh_(cn);
                unsigned short h1b =
                    *(const unsigned short*)(As + lds_off(rib, 16 + (j >> 3)) + (j & 7) * 2);
                const bool keep = (n == eb) || (n == rbn);
                *(unsigned short*)(Cs + cs_off(rib, 32 + (j >> 3)) + (j & 7) * 2) =
                    keep ? bfu(cold) : bfu(cn);
                *(unsigned short*)(Cs + cs_off(rib, 48 + (j >> 3)) + (j & 7) * 2) =
                    keep ? h1b : bfu(hn);
            }
        }
    __syncthreads();   // Cs complete; As h1-reads done -> safe to overwrite As

    // ---- stage dec weights into As (f32): [0..1023]=rW, [1024..2047]=bW ----
    float* dw = (float*)As;
    ((float4*)dw)[t]       = ((const float4*)rW)[t];
    ((float4*)dw)[256 + t] = ((const float4*)bW)[t];
    __syncthreads();

    // ---- store Cs -> contrib, fully coalesced 16B stores ----
    #pragma unroll
    for (int i = 0; i < 8; ++i) {
        const int idx = i * 256 + t;
        const int r = idx >> 6, u = idx & 63;
        short8 v = *(const short8*)(Cs + cs_off(r, u));
        *(short8*)(contrib + (size_t)(row0 + r) * H4c + u * 8) = v;
    }

    // ---- fused decision head: 8 lanes per row, 8 rows per wave ----
    {
        const int row  = wave * 8 + (l >> 3);   // 0..31
        const int s    = l & 7;                 // 64-col slice
        const int grow = row0 + row;
        float pr0 = 0.f, pr1 = 0.f, pb0 = 0.f, pb1 = 0.f;
        #pragma unroll
        for (int cu = 0; cu < 8; ++cu) {
            short8 ev = *(const short8*)(Cs + cs_off(row, s * 8 + cu));
            const float4* rp = (const float4*)(dw + (s * 64 + cu * 8) * 2);
            const float4* bp = (const float4*)(dw + 1024 + (s * 64 + cu * 8) * 2);
            #pragma unroll
            for (int q = 0; q < 4; ++q) {
                float4 rv = rp[q], bv = bp[q];
                float e0 = bf2f((unsigned short)ev[q * 2]);
                float e1 = bf2f((unsigned short)ev[q * 2 + 1]);
                pr0 += e0 * rv.x + e1 * rv.z;
                pr1 += e0 * rv.y + e1 * rv.w;
                pb0 += e0 * bv.x + e1 * bv.z;
                pb1 += e0 * bv.y + e1 * bv.w;
            }
        }
        #pragma unroll
        for (int m = 1; m < 8; m <<= 1) {
            pr0 += __shfl_xor(pr0, m);
            pr1 += __shfl_xor(pr1, m);
            pb0 += __shfl_xor(pb0, m);
            pb1 += __shfl_xor(pb1, m);
        }
        if (s == 0) {
            const int n = grow & (Nc - 1);
            float r0v = pr0 + rbv[0], r1v = pr1 + rbv[1];
            float m  = fmaxf(r0v, r1v);
            float z0 = __expf(r0v - m), z1 = __expf(r1v - m);
            float inv = 1.f / (z0 + z1);
            float praise = z0 * inv, pno = z1 * inv;
            if (n == eb) { praise = 0.f; pno = 1.f; }
            float q0 = pb0 + bbv[0], q1 = pb1 + bbv[1];
            float mm = fmaxf(q0, q1);
            float y0 = __expf(q0 - mm), y1 = __expf(q1 - mm);
            float binv = 1.f / (y0 + y1);
            float ipv = ip_in[grow];
            w_all[grow]            = praise * ipv;
            w_all[BNc + grow]      = pno * y0 * binv * ipv;
            w_all[2 * BNc + grow]  = pno * y1 * binv * ipv;
        }
    }
}

// ---------------------------------------------------------------------------
// Invert the scatter into per-target linked lists. e = row*4 + type.
// ---------------------------------------------------------------------------
__global__ __launch_bounds__(256) void build_kernel(
    const int* __restrict__ t_idx, const int* __restrict__ f_idx,
    const int* __restrict__ r_idx, int* __restrict__ head, int* __restrict__ nxt)
{
    const int row  = blockIdx.x * 256 + threadIdx.x;
    const int base = (row >> 11) << 11;
    const int e0 = row * 4;
    int o;
    o = atomicExch(&head[base + r_idx[row]], e0);     nxt[e0]     = o;
    o = atomicExch(&head[base + t_idx[row]], e0 + 1); nxt[e0 + 1] = o;
    o = atomicExch(&head[base + f_idx[row]], e0 + 2); nxt[e0 + 2] = o;
}

// ---------------------------------------------------------------------------
// Gather: one wave per target (b,m). bf16 contrib rows, f32 accumulate.
// ---------------------------------------------------------------------------
__global__ __launch_bounds__(256) void gather_kernel(
    const unsigned short* __restrict__ contrib, const float* __restrict__ w_all,
    const int* __restrict__ head, const int* __restrict__ nxt,
    const float* __restrict__ c0_in, const float* __restrict__ h0_in,
    const float* __restrict__ c1_in, const float* __restrict__ h1_in,
    const float* __restrict__ ip_in,
    const int* __restrict__ cstep, const int* __restrict__ slim,
    float* __restrict__ out)
{
    const int gtid = blockIdx.x * 256 + threadIdx.x;
    const int wid  = gtid >> 6;
    const int l    = gtid & 63;
    const int bidx = wid >> 11;

    float acc[8] = {0.f, 0.f, 0.f, 0.f, 0.f, 0.f, 0.f, 0.f};
    float ipsum = 0.f;

    int e = head[wid];
    while (e >= 0) {
        const int src = e >> 2;
        const float w = w_all[(e & 3) * BNc + src];
        const unsigned short* crow = contrib + (size_t)src * 512;
        #pragma unroll
        for (int q = 0; q < 8; ++q) acc[q] += w * bf2f(crow[q * 64 + l]);
        ipsum += w;
        e = nxt[e];
    }

    const bool live = cstep[bidx] < slim[bidx];
    float* orow = out + (size_t)wid * 513;
    if (live) {
        const float inv = 1.f / (ipsum + 1e-7f);
        #pragma unroll
        for (int q = 0; q < 8; ++q) orow[q * 64 + l] = acc[q] * inv;
        if (l == 0) orow[512] = ipsum;
    } else {
        #pragma unroll
        for (int q = 0; q < 8; ++q) {
            const int off = (q & 1) * 64 + l;
            const float* p = (q >> 1) == 0 ? c0_in : (q >> 1) == 1 ? h0_in
                           : (q >> 1) == 2 ? c1_in : h1_in;
            orow[q * 64 + l] = p[(size_t)wid * Hc + off];
        }
        if (l == 0) orow[512] = ip_in[wid];
    }
}

extern "C" void kernel_launch(void* const* d_in, const int* in_sizes, int n_in,
                              void* d_out, int out_size, void* d_ws, size_t ws_size,
                              hipStream_t stream) {
    const float* x     = (const float*)d_in[0];
    const float* c0    = (const float*)d_in[1];
    const float* h0    = (const float*)d_in[2];
    const float* c1    = (const float*)d_in[3];
    const float* h1    = (const float*)d_in[4];
    const float* ip    = (const float*)d_in[5];
    const float* Wx0   = (const float*)d_in[6];
    const float* Wh0   = (const float*)d_in[7];
    const float* b0    = (const float*)d_in[8];
    const float* Wx1   = (const float*)d_in[9];
    const float* Wh1   = (const float*)d_in[10];
    const float* b1    = (const float*)d_in[11];
    const float* rW    = (const float*)d_in[12];
    const float* rb    = (const float*)d_in[13];
    const float* bW    = (const float*)d_in[14];
    const float* bb    = (const float*)d_in[15];
    const int* t_idx   = (const int*)d_in[16];
    const int* f_idx   = (const int*)d_in[17];
    const int* r_idx   = (const int*)d_in[18];
    const int* exit_i  = (const int*)d_in[19];
    const int* raise_i = (const int*)d_in[20];
    const int* cstep   = (const int*)d_in[21];
    const int* slim    = (const int*)d_in[22];
    float* out = (float*)d_out;

    // workspace layout
    unsigned short* contrib = (unsigned short*)d_ws;            // BN*512 bf16 (64 MiB)
    unsigned short* W0T = contrib + (size_t)BNc * 512;          // 512*256 bf16
    unsigned short* W1T = W0T + 512 * 256;
    float* w_all = (float*)(W1T + 512 * 256);                   // 3*BN f32
    int*   head  = (int*)(w_all + 3 * (size_t)BNc);             // BN int
    int*   nxt   = head + BNc;                                  // 4*BN int

    hipMemsetAsync(head, 0xFF, BNc * sizeof(int), stream);

    prep_kernel<<<512, 256, 0, stream>>>(Wx0, Wh0, Wx1, Wh1, W0T, W1T);
    lstm_mfma_kernel<<<BNc / 32, 256, 0, stream>>>(x, c0, h0, c1, h1,
                                                   W0T, W1T, b0, b1,
                                                   rW, rb, bW, bb, ip,
                                                   exit_i, raise_i, contrib, w_all);
    build_kernel<<<BNc / 256, 256, 0, stream>>>(t_idx, f_idx, r_idx, head, nxt);
    gather_kernel<<<BNc / 4, 256, 0, stream>>>(contrib, w_all, head, nxt,
                                               c0, h0, c1, h1, ip, cstep, slim, out);
}